// Round 2
// 2133.106 us; speedup vs baseline: 1.2812x; 1.2812x over previous
//
#include <hip/hip_runtime.h>
#include <math.h>

#define BB 64
#define SS 512
#define EE 256
#define HH 512

// ---------------------------------------------------------------------------
// Projection GEMM (layer 0 only now): out[m][n] = sum_k A[m][k]*Wih[n][k]+b1+b2
// ---------------------------------------------------------------------------
template <int K>
__global__ __launch_bounds__(256) void k_proj(const float* __restrict__ Ain,
                                              const int* __restrict__ src,
                                              const float* __restrict__ emb,
                                              const float* __restrict__ Wih,
                                              const float* __restrict__ b1,
                                              const float* __restrict__ b2,
                                              float* __restrict__ out) {
    __shared__ __align__(16) float As[16][68];
    __shared__ __align__(16) float Bs[16][68];
    int tid = threadIdx.x;
    int m0 = blockIdx.x * 64;
    int n0 = blockIdx.y * 64;
    int tx = tid & 15, ty = tid >> 4;
    int lr = tid >> 2;
    int lc = (tid & 3) * 4;

    const float* arow;
    if (src) arow = emb + (size_t)src[m0 + lr] * EE;
    else     arow = Ain + (size_t)(m0 + lr) * K;
    const float* brow = Wih + (size_t)(n0 + lr) * K;

    float acc[4][4] = {};

    for (int k0 = 0; k0 < K; k0 += 16) {
        float4 av = *(const float4*)(arow + k0 + lc);
        float4 bv = *(const float4*)(brow + k0 + lc);
        __syncthreads();
        As[lc + 0][lr] = av.x; As[lc + 1][lr] = av.y;
        As[lc + 2][lr] = av.z; As[lc + 3][lr] = av.w;
        Bs[lc + 0][lr] = bv.x; Bs[lc + 1][lr] = bv.y;
        Bs[lc + 2][lr] = bv.z; Bs[lc + 3][lr] = bv.w;
        __syncthreads();
#pragma unroll
        for (int k = 0; k < 16; ++k) {
            float4 a = *(const float4*)&As[k][ty * 4];
            float4 b = *(const float4*)&Bs[k][tx * 4];
            acc[0][0] += a.x * b.x; acc[0][1] += a.x * b.y;
            acc[0][2] += a.x * b.z; acc[0][3] += a.x * b.w;
            acc[1][0] += a.y * b.x; acc[1][1] += a.y * b.y;
            acc[1][2] += a.y * b.z; acc[1][3] += a.y * b.w;
            acc[2][0] += a.z * b.x; acc[2][1] += a.z * b.y;
            acc[2][2] += a.z * b.z; acc[2][3] += a.z * b.w;
            acc[3][0] += a.w * b.x; acc[3][1] += a.w * b.y;
            acc[3][2] += a.w * b.z; acc[3][3] += a.w * b.w;
        }
    }

    int n = n0 + tx * 4;
    float bx_ = b1[n + 0] + b2[n + 0];
    float by_ = b1[n + 1] + b2[n + 1];
    float bz_ = b1[n + 2] + b2[n + 2];
    float bw_ = b1[n + 3] + b2[n + 3];
#pragma unroll
    for (int i = 0; i < 4; ++i) {
        int m = m0 + ty * 4 + i;
        float4 o;
        o.x = acc[i][0] + bx_; o.y = acc[i][1] + by_;
        o.z = acc[i][2] + bz_; o.w = acc[i][3] + bw_;
        *(float4*)(out + (size_t)m * HH + n) = o;
    }
}

// ---------------------------------------------------------------------------
// Fused 2-layer persistent recurrence, software-pipelined across layers.
// Tick t (t=1..512) computes layer0 h0[t] (t<512) AND layer1 h1[t-1].
// Serial chain: 513 ticks instead of 1024 (two sequential 512-step scans).
//
// Grid = 256 blocks = 32 pairs (2 batches) x 8 row-slices (64 rows).
// 512 threads = 64 lanes (row r) x 8 waves (k-eighth w, 64 k-values each).
// Three 64x512 weight slices per block (W_hh0, W_ih1, W_hh1) live in
// registers: 48 float4 = 192 regs/thread (VGPR+AGPR unified, cap 256 via
// __launch_bounds__(512,2); 1 block/CU register-forced -> all co-resident).
//
// Exchange: tag-in-data {f32 val, u32 tag} 8B relaxed agent atomics, 2-slot
// buffers, per-layer (hp0: h0/y0, hp1: h1). Tag conventions: h0[s] tag s+1,
// h1[s] tag s+2 -> tick t polls tag==t at slot t&1 in BOTH buffers.
// 2-slot safe: publishing tag t+1 (end of tick t) requires this block passed
// the tag-t poll, which requires all group blocks published tag t (end of
// tick t-1), which requires they all passed the tag t-1 poll. Poison/stale
// tags from a previous identical run carry identical values (deterministic
// inputs), 0xAA poison never matches tags 1..512.
// Waves 0-3 poll hp0, waves 4-7 poll hp1 (wave-uniform; 4 pairs/thread).
// ---------------------------------------------------------------------------
__global__ __launch_bounds__(512, 2) void k_rec_fused(
    const float* __restrict__ pre,       // [B][S][H] layer0 input projection
    const float* __restrict__ Whh0,
    const float* __restrict__ Wih1,
    const float* __restrict__ Whh1,
    const float* __restrict__ b_ih1,
    const float* __restrict__ b_hh1,
    float* __restrict__ y,               // [B][S][H] layer1 output
    float* __restrict__ hlast,           // [2][B][H]
    unsigned long long* __restrict__ hp0,
    unsigned long long* __restrict__ hp1) {
    __shared__ __align__(16) float h0_lds[2 * HH];   // 2 batches x 512
    __shared__ __align__(16) float h1_lds[2 * HH];
    __shared__ __align__(16) float red[8][6][64];    // [w][unit*2+batch][row]

    const int tid = threadIdx.x;
    const int r = tid & 63;
    const int w = tid >> 6;              // k-eighth 0..7 (batch idx when w<2)
    const int bid = blockIdx.x;
    const int g = bid & 7;               // row slice
    const int c = bid >> 3;              // batch pair
    const int grow = g * 64 + r;
    const int b = c * 2 + (w & 1);       // batch for finalize (valid w<2)

    // poll assignment: waves 0-3 -> hp0/h0_lds, waves 4-7 -> hp1/h1_lds
    const int half = tid >> 8;
    const int j4 = (tid & 255) * 4;
    unsigned long long* __restrict__ mybuf = half ? hp1 : hp0;
    float* __restrict__ mylds = half ? h1_lds : h0_lds;

    // three weight slices -> registers (one-time)
    float4 w0[16], wa[16], wb[16];
    {
        const float* p0 = Whh0 + (size_t)grow * HH + w * 64;
        const float* pa = Wih1 + (size_t)grow * HH + w * 64;
        const float* pb = Whh1 + (size_t)grow * HH + w * 64;
#pragma unroll
        for (int i = 0; i < 16; ++i) {
            w0[i] = *(const float4*)(p0 + i * 4);
            wa[i] = *(const float4*)(pa + i * 4);
            wb[i] = *(const float4*)(pb + i * 4);
        }
    }

    // ---- prologue: h0[0] = tanh(pre[0]) tag 1; h1[-1] = 0 tag 1 (slot 1) ----
    float h0last = 0.f, h1last = 0.f, bias1 = 0.f;
    if (w < 2) {
        bias1 = b_ih1[grow] + b_hh1[grow];
        float pv0 = pre[(size_t)b * SS * HH + grow];
        h0last = tanhf(pv0);
        unsigned long long pk0 = ((unsigned long long)1u << 32) |
                                 (unsigned long long)__float_as_uint(h0last);
        __hip_atomic_store(&hp0[(size_t)1 * BB * HH + (size_t)b * HH + grow], pk0,
                           __ATOMIC_RELAXED, __HIP_MEMORY_SCOPE_AGENT);
        unsigned long long pk1 = ((unsigned long long)1u << 32);  // h1[-1]=0
        __hip_atomic_store(&hp1[(size_t)1 * BB * HH + (size_t)b * HH + grow], pk1,
                           __ATOMIC_RELAXED, __HIP_MEMORY_SCOPE_AGENT);
    }

    for (int t = 1; t <= SS; ++t) {
        // prefetch layer0 pre value (hides under poll + matvec)
        float pv = 0.f;
        if (w < 2 && t < SS) pv = pre[((size_t)b * SS + t) * HH + grow];

        // consume: h0[t-1] (hp0) and h1[t-2] (hp1), tags must equal t
        const unsigned long long* srcp =
            mybuf + (size_t)(t & 1) * BB * HH + (size_t)(c * 2) * HH + j4;
        unsigned long long p0, p1, p2, p3;
        const unsigned tt = (unsigned)t;
        for (;;) {
            p0 = __hip_atomic_load(&srcp[0], __ATOMIC_RELAXED, __HIP_MEMORY_SCOPE_AGENT);
            p1 = __hip_atomic_load(&srcp[1], __ATOMIC_RELAXED, __HIP_MEMORY_SCOPE_AGENT);
            p2 = __hip_atomic_load(&srcp[2], __ATOMIC_RELAXED, __HIP_MEMORY_SCOPE_AGENT);
            p3 = __hip_atomic_load(&srcp[3], __ATOMIC_RELAXED, __HIP_MEMORY_SCOPE_AGENT);
            unsigned d = (((unsigned)(p0 >> 32)) ^ tt) | (((unsigned)(p1 >> 32)) ^ tt) |
                         (((unsigned)(p2 >> 32)) ^ tt) | (((unsigned)(p3 >> 32)) ^ tt);
            if (d == 0) break;
        }
        float4 hv;
        hv.x = __uint_as_float((unsigned)p0);
        hv.y = __uint_as_float((unsigned)p1);
        hv.z = __uint_as_float((unsigned)p2);
        hv.w = __uint_as_float((unsigned)p3);
        *(float4*)&mylds[j4] = hv;
        __syncthreads();

        // three matvec units over this thread's 64-value k-eighth:
        //   a: W_hh0 * h0[t-1]   (layer0 recurrence)
        //   i: W_ih1 * h0[t-1]   (layer1 input proj, same h0 operand)
        //   h: W_hh1 * h1[t-2]   (layer1 recurrence)
        float a00 = 0.f, a01 = 0.f, ai0 = 0.f, ai1 = 0.f, ah0 = 0.f, ah1 = 0.f;
        const float4* xb0 = (const float4*)h0_lds + (w << 4);
        const float4* xb1 = (const float4*)(h0_lds + HH) + (w << 4);
        const float4* zb0 = (const float4*)h1_lds + (w << 4);
        const float4* zb1 = (const float4*)(h1_lds + HH) + (w << 4);
#pragma unroll
        for (int i = 0; i < 16; ++i) {
            const float4 A = w0[i];
            const float4 Bw = wa[i];
            const float4 Cw = wb[i];
            const float4 x0 = xb0[i];
            const float4 x1 = xb1[i];
            const float4 z0 = zb0[i];
            const float4 z1 = zb1[i];
            a00 += A.x * x0.x;  a00 += A.y * x0.y;  a00 += A.z * x0.z;  a00 += A.w * x0.w;
            a01 += A.x * x1.x;  a01 += A.y * x1.y;  a01 += A.z * x1.z;  a01 += A.w * x1.w;
            ai0 += Bw.x * x0.x; ai0 += Bw.y * x0.y; ai0 += Bw.z * x0.z; ai0 += Bw.w * x0.w;
            ai1 += Bw.x * x1.x; ai1 += Bw.y * x1.y; ai1 += Bw.z * x1.z; ai1 += Bw.w * x1.w;
            ah0 += Cw.x * z0.x; ah0 += Cw.y * z0.y; ah0 += Cw.z * z0.z; ah0 += Cw.w * z0.w;
            ah1 += Cw.x * z1.x; ah1 += Cw.y * z1.y; ah1 += Cw.z * z1.z; ah1 += Cw.w * z1.w;
        }
        red[w][0][r] = a00; red[w][1][r] = a01;
        red[w][2][r] = ai0; red[w][3][r] = ai1;
        red[w][4][r] = ah0; red[w][5][r] = ah1;
        __syncthreads();

        if (w < 2) {
            float s0 = 0.f, si = 0.f, sh = 0.f;
#pragma unroll
            for (int q = 0; q < 8; ++q) {
                s0 += red[q][0 + w][r];
                si += red[q][2 + w][r];
                sh += red[q][4 + w][r];
            }
            if (t < SS) {
                // layer0: h0[t] = tanh(pre[t] + W_hh0*h0[t-1]); publish first
                // (it feeds BOTH units of every consumer next tick)
                float h0v = tanhf(pv + s0);
                h0last = h0v;
                unsigned long long pk0 =
                    ((unsigned long long)(unsigned)(t + 1) << 32) |
                    (unsigned long long)__float_as_uint(h0v);
                __hip_atomic_store(&hp0[(size_t)((t + 1) & 1) * BB * HH + (size_t)b * HH + grow],
                                   pk0, __ATOMIC_RELAXED, __HIP_MEMORY_SCOPE_AGENT);
            }
            // layer1: h1[t-1] = tanh(W_ih1*h0[t-1] + W_hh1*h1[t-2] + biases)
            float h1v = tanhf(si + sh + bias1);
            h1last = h1v;
            if (t < SS) {
                unsigned long long pk1 =
                    ((unsigned long long)(unsigned)(t + 1) << 32) |
                    (unsigned long long)__float_as_uint(h1v);
                __hip_atomic_store(&hp1[(size_t)((t + 1) & 1) * BB * HH + (size_t)b * HH + grow],
                                   pk1, __ATOMIC_RELAXED, __HIP_MEMORY_SCOPE_AGENT);
            }
            y[((size_t)b * SS + (t - 1)) * HH + grow] = h1v;
        }
    }
    if (w < 2) {
        hlast[(size_t)b * HH + grow] = h0last;                          // layer0
        hlast[(size_t)BB * HH + (size_t)b * HH + grow] = h1last;        // layer1
    }
}

// ---------------------------------------------------------------------------
extern "C" void kernel_launch(void* const* d_in, const int* in_sizes, int n_in,
                              void* d_out, int out_size, void* d_ws, size_t ws_size,
                              hipStream_t stream) {
    const int*   src   = (const int*)d_in[0];
    const float* emb   = (const float*)d_in[1];
    const float* W_ih0 = (const float*)d_in[2];
    const float* W_hh0 = (const float*)d_in[3];
    const float* b_ih0 = (const float*)d_in[4];
    const float* b_hh0 = (const float*)d_in[5];
    const float* W_ih1 = (const float*)d_in[6];
    const float* W_hh1 = (const float*)d_in[7];
    const float* b_ih1 = (const float*)d_in[8];
    const float* b_hh1 = (const float*)d_in[9];

    float* out   = (float*)d_out;
    float* y_out = out;                               // [B][S][H] (layer1 y)
    float* hlast = out + (size_t)BB * SS * HH;        // [2][B][H]

    float* ws  = (float*)d_ws;
    float* pre = ws;                                  // [B][S][H] layer0 proj
    unsigned long long* hp0 = (unsigned long long*)(ws + (size_t)BB * SS * HH);
    unsigned long long* hp1 = hp0 + (size_t)2 * BB * HH;

    // Layer-0 input projection (embedding gather fused in)
    k_proj<EE><<<dim3(512, 8), 256, 0, stream>>>(nullptr, src, emb, W_ih0,
                                                 b_ih0, b_hh0, pre);
    // Fused pipelined 2-layer recurrence (layer1 input proj folded in)
    k_rec_fused<<<256, 512, 0, stream>>>(pre, W_hh0, W_ih1, W_hh1, b_ih1, b_hh1,
                                         y_out, hlast, hp0, hp1);
}

// Round 6
// 2120.204 us; speedup vs baseline: 1.2890x; 1.0061x over previous
//
#include <hip/hip_runtime.h>
#include <math.h>

#define BB 64
#define SS 512
#define EE 256
#define HH 512

// ---------------------------------------------------------------------------
// Projection GEMM (layer 0): out[m][n] = sum_k A[m][k]*Wih[n][k] + b1 + b2
// ---------------------------------------------------------------------------
template <int K>
__global__ __launch_bounds__(256) void k_proj(const float* __restrict__ Ain,
                                              const int* __restrict__ src,
                                              const float* __restrict__ emb,
                                              const float* __restrict__ Wih,
                                              const float* __restrict__ b1,
                                              const float* __restrict__ b2,
                                              float* __restrict__ out) {
    __shared__ __align__(16) float As[16][68];
    __shared__ __align__(16) float Bs[16][68];
    int tid = threadIdx.x;
    int m0 = blockIdx.x * 64;
    int n0 = blockIdx.y * 64;
    int tx = tid & 15, ty = tid >> 4;
    int lr = tid >> 2;
    int lc = (tid & 3) * 4;

    const float* arow;
    if (src) arow = emb + (size_t)src[m0 + lr] * EE;
    else     arow = Ain + (size_t)(m0 + lr) * K;
    const float* brow = Wih + (size_t)(n0 + lr) * K;

    float acc[4][4] = {};

    for (int k0 = 0; k0 < K; k0 += 16) {
        float4 av = *(const float4*)(arow + k0 + lc);
        float4 bv = *(const float4*)(brow + k0 + lc);
        __syncthreads();
        As[lc + 0][lr] = av.x; As[lc + 1][lr] = av.y;
        As[lc + 2][lr] = av.z; As[lc + 3][lr] = av.w;
        Bs[lc + 0][lr] = bv.x; Bs[lc + 1][lr] = bv.y;
        Bs[lc + 2][lr] = bv.z; Bs[lc + 3][lr] = bv.w;
        __syncthreads();
#pragma unroll
        for (int k = 0; k < 16; ++k) {
            float4 a = *(const float4*)&As[k][ty * 4];
            float4 b = *(const float4*)&Bs[k][tx * 4];
            acc[0][0] += a.x * b.x; acc[0][1] += a.x * b.y;
            acc[0][2] += a.x * b.z; acc[0][3] += a.x * b.w;
            acc[1][0] += a.y * b.x; acc[1][1] += a.y * b.y;
            acc[1][2] += a.y * b.z; acc[1][3] += a.y * b.w;
            acc[2][0] += a.z * b.x; acc[2][1] += a.z * b.y;
            acc[2][2] += a.z * b.z; acc[2][3] += a.z * b.w;
            acc[3][0] += a.w * b.x; acc[3][1] += a.w * b.y;
            acc[3][2] += a.w * b.z; acc[3][3] += a.w * b.w;
        }
    }

    int n = n0 + tx * 4;
    float bx_ = b1[n + 0] + b2[n + 0];
    float by_ = b1[n + 1] + b2[n + 1];
    float bz_ = b1[n + 2] + b2[n + 2];
    float bw_ = b1[n + 3] + b2[n + 3];
#pragma unroll
    for (int i = 0; i < 4; ++i) {
        int m = m0 + ty * 4 + i;
        float4 o;
        o.x = acc[i][0] + bx_; o.y = acc[i][1] + by_;
        o.z = acc[i][2] + bz_; o.w = acc[i][3] + bw_;
        *(float4*)(out + (size_t)m * HH + n) = o;
    }
}

// ---------------------------------------------------------------------------
// Fused 2-layer persistent recurrence with BATCH-PHASED exchange pipelining.
// Each tick t has two sequential half-ticks: phase A (batch 2c), phase B
// (batch 2c+1). The two batches are independent serial chains sharing the
// same weight registers; processing them back-to-back means each phase's
// poll targets data published one full opposite-phase (~2000+ cyc) earlier,
// so the IC round-trip is hidden and polls hit on the first attempt.
//
// Per half-tick (batch X), tick t computes h0_X(t) and h1_X(t-1) (1-step
// layer skew as before). 3 matvec units: W_hh0*h0, W_ih1*h0, W_hh1*h1.
// Grid 256 blocks = 32 chunks x 8 row-slices; 512 thr = 64 rows x 8 k-eighths.
// Weights: 48 float4/thread in unified VGPR+AGPR file (launch_bounds(512,2)).
//
// Exchange: identical tag-in-data {f32,u32 tag} 8B relaxed agent atomics,
// 2-slot per-layer buffers (hp0: h0, hp1: h1). Tick-t poll wants tag t in
// slot t&1; publish tag t+1 into slot (t+1)&1. 2-slot induction per batch
// chain unchanged. Waves 0-3 poll hp0, waves 4-7 poll hp1; 2 pairs/thread
// per phase (1024 pairs = h0_X:512 + h1_X:512).
// ---------------------------------------------------------------------------
__device__ __forceinline__ void rec_phase(
    int t, int bX, int grow, int r, int w, int half, int j2,
    const float* __restrict__ pre,
    const float4* w0, const float4* wa, const float4* wb, float bias1,
    unsigned long long* __restrict__ hp0, unsigned long long* __restrict__ hp1,
    float* __restrict__ h0L, float* __restrict__ h1L, float (*red)[3][64],
    float* __restrict__ y, float& h0last, float& h1last) {
    // prefetch this batch's pre value (wave 0 only; hides under poll+FMA)
    float pv = 0.f;
    if (w == 0 && t < SS) pv = pre[((size_t)bX * SS + t) * HH + grow];

    // poll: 2 pairs/thread, tags must equal t
    unsigned long long* mybuf = half ? hp1 : hp0;
    float* mylds = half ? h1L : h0L;
    const unsigned long long* srcp =
        mybuf + (size_t)(t & 1) * BB * HH + (size_t)bX * HH + j2;
    unsigned long long p0, p1;
    const unsigned tt = (unsigned)t;
    for (;;) {
        p0 = __hip_atomic_load(&srcp[0], __ATOMIC_RELAXED, __HIP_MEMORY_SCOPE_AGENT);
        p1 = __hip_atomic_load(&srcp[1], __ATOMIC_RELAXED, __HIP_MEMORY_SCOPE_AGENT);
        unsigned d = (((unsigned)(p0 >> 32)) ^ tt) | (((unsigned)(p1 >> 32)) ^ tt);
        if (d == 0) break;
    }
    float2 hv;
    hv.x = __uint_as_float((unsigned)p0);
    hv.y = __uint_as_float((unsigned)p1);
    *(float2*)&mylds[j2] = hv;
    __syncthreads();

    // 3 matvec units over this thread's 64-value k-eighth, single batch
    float aa = 0.f, ai = 0.f, ah = 0.f;
    const float4* xb = (const float4*)h0L + (w << 4);
    const float4* zb = (const float4*)h1L + (w << 4);
#pragma unroll
    for (int i = 0; i < 16; ++i) {
        const float4 A = w0[i];
        const float4 Bw = wa[i];
        const float4 Cw = wb[i];
        const float4 x = xb[i];
        const float4 z = zb[i];
        aa += A.x * x.x;  aa += A.y * x.y;  aa += A.z * x.z;  aa += A.w * x.w;
        ai += Bw.x * x.x; ai += Bw.y * x.y; ai += Bw.z * x.z; ai += Bw.w * x.w;
        ah += Cw.x * z.x; ah += Cw.y * z.y; ah += Cw.z * z.z; ah += Cw.w * z.w;
    }
    red[w][0][r] = aa; red[w][1][r] = ai; red[w][2][r] = ah;
    __syncthreads();

    // finalize: wave 0 -> h0_X(t) (layer0); wave 1 -> h1_X(t-1) (layer1)
    if (w == 0) {
        if (t < SS) {
            float s0 = red[0][0][r] + red[1][0][r] + red[2][0][r] + red[3][0][r] +
                       red[4][0][r] + red[5][0][r] + red[6][0][r] + red[7][0][r];
            float h0v = tanhf(pv + s0);
            h0last = h0v;
            unsigned long long pk =
                ((unsigned long long)(unsigned)(t + 1) << 32) |
                (unsigned long long)__float_as_uint(h0v);
            __hip_atomic_store(&hp0[(size_t)((t + 1) & 1) * BB * HH + (size_t)bX * HH + grow],
                               pk, __ATOMIC_RELAXED, __HIP_MEMORY_SCOPE_AGENT);
        }
    } else if (w == 1) {
        float si = red[0][1][r] + red[1][1][r] + red[2][1][r] + red[3][1][r] +
                   red[4][1][r] + red[5][1][r] + red[6][1][r] + red[7][1][r];
        float sh = red[0][2][r] + red[1][2][r] + red[2][2][r] + red[3][2][r] +
                   red[4][2][r] + red[5][2][r] + red[6][2][r] + red[7][2][r];
        float h1v = tanhf(si + sh + bias1);
        h1last = h1v;
        y[((size_t)bX * SS + (t - 1)) * HH + grow] = h1v;
        if (t < SS) {
            unsigned long long pk =
                ((unsigned long long)(unsigned)(t + 1) << 32) |
                (unsigned long long)__float_as_uint(h1v);
            __hip_atomic_store(&hp1[(size_t)((t + 1) & 1) * BB * HH + (size_t)bX * HH + grow],
                               pk, __ATOMIC_RELAXED, __HIP_MEMORY_SCOPE_AGENT);
        }
    }
}

__global__ __launch_bounds__(512, 2) void k_rec_fused2(
    const float* __restrict__ pre,       // [B][S][H] layer0 input projection
    const float* __restrict__ Whh0,
    const float* __restrict__ Wih1,
    const float* __restrict__ Whh1,
    const float* __restrict__ b_ih1,
    const float* __restrict__ b_hh1,
    float* __restrict__ y,               // [B][S][H] layer1 output
    float* __restrict__ hlast,           // [2][B][H]
    unsigned long long* __restrict__ hp0,
    unsigned long long* __restrict__ hp1) {
    __shared__ __align__(16) float h0A[HH], h1A[HH], h0B[HH], h1B[HH];
    __shared__ __align__(16) float redA[8][3][64], redB[8][3][64];

    const int tid = threadIdx.x;
    const int r = tid & 63;
    const int w = tid >> 6;              // k-eighth 0..7
    const int bid = blockIdx.x;
    const int g = bid & 7;               // row slice (XCD = g for weight L2 locality)
    const int c = bid >> 3;              // batch chunk
    const int grow = g * 64 + r;
    const int bA = c * 2, bB = c * 2 + 1;

    const int half = tid >> 8;           // waves 0-3: hp0/h0; waves 4-7: hp1/h1
    const int j2 = (tid & 255) * 2;      // 2 pairs/thread per phase

    // three 64x512 weight slices -> unified register file (one-time)
    float4 w0[16], wa[16], wb[16];
    {
        const float* p0 = Whh0 + (size_t)grow * HH + w * 64;
        const float* pa = Wih1 + (size_t)grow * HH + w * 64;
        const float* pb = Whh1 + (size_t)grow * HH + w * 64;
#pragma unroll
        for (int i = 0; i < 16; ++i) {
            w0[i] = *(const float4*)(p0 + i * 4);
            wa[i] = *(const float4*)(pa + i * 4);
            wb[i] = *(const float4*)(pb + i * 4);
        }
    }

    // ---- prologue: per batch, h0(0)=tanh(pre[0]) tag 1; h1(-1)=0 tag 1 ----
    float h0lA = 0.f, h0lB = 0.f, h1lA = 0.f, h1lB = 0.f, bias1 = 0.f;
    if (w == 0) {
        float pA = pre[(size_t)bA * SS * HH + grow];
        h0lA = tanhf(pA);
        unsigned long long pk = ((unsigned long long)1u << 32) |
                                (unsigned long long)__float_as_uint(h0lA);
        __hip_atomic_store(&hp0[(size_t)1 * BB * HH + (size_t)bA * HH + grow], pk,
                           __ATOMIC_RELAXED, __HIP_MEMORY_SCOPE_AGENT);
        float pB = pre[(size_t)bB * SS * HH + grow];
        h0lB = tanhf(pB);
        pk = ((unsigned long long)1u << 32) |
             (unsigned long long)__float_as_uint(h0lB);
        __hip_atomic_store(&hp0[(size_t)1 * BB * HH + (size_t)bB * HH + grow], pk,
                           __ATOMIC_RELAXED, __HIP_MEMORY_SCOPE_AGENT);
    } else if (w == 1) {
        bias1 = b_ih1[grow] + b_hh1[grow];
        unsigned long long pk = ((unsigned long long)1u << 32);  // h1(-1)=0
        __hip_atomic_store(&hp1[(size_t)1 * BB * HH + (size_t)bA * HH + grow], pk,
                           __ATOMIC_RELAXED, __HIP_MEMORY_SCOPE_AGENT);
        __hip_atomic_store(&hp1[(size_t)1 * BB * HH + (size_t)bB * HH + grow], pk,
                           __ATOMIC_RELAXED, __HIP_MEMORY_SCOPE_AGENT);
    }

    for (int t = 1; t <= SS; ++t) {
        // phase A (batch 2c): its tag-t data was published one B-phase ago
        rec_phase(t, bA, grow, r, w, half, j2, pre, w0, wa, wb, bias1,
                  hp0, hp1, h0A, h1A, redA, y, h0lA, h1lA);
        // phase B (batch 2c+1): its tag-t data was published one A-phase ago
        rec_phase(t, bB, grow, r, w, half, j2, pre, w0, wa, wb, bias1,
                  hp0, hp1, h0B, h1B, redB, y, h0lB, h1lB);
    }

    if (w == 0) {
        hlast[(size_t)bA * HH + grow] = h0lA;                        // layer0
        hlast[(size_t)bB * HH + grow] = h0lB;
    } else if (w == 1) {
        hlast[(size_t)BB * HH + (size_t)bA * HH + grow] = h1lA;      // layer1
        hlast[(size_t)BB * HH + (size_t)bB * HH + grow] = h1lB;
    }
}

// ---------------------------------------------------------------------------
extern "C" void kernel_launch(void* const* d_in, const int* in_sizes, int n_in,
                              void* d_out, int out_size, void* d_ws, size_t ws_size,
                              hipStream_t stream) {
    const int*   src   = (const int*)d_in[0];
    const float* emb   = (const float*)d_in[1];
    const float* W_ih0 = (const float*)d_in[2];
    const float* W_hh0 = (const float*)d_in[3];
    const float* b_ih0 = (const float*)d_in[4];
    const float* b_hh0 = (const float*)d_in[5];
    const float* W_ih1 = (const float*)d_in[6];
    const float* W_hh1 = (const float*)d_in[7];
    const float* b_ih1 = (const float*)d_in[8];
    const float* b_hh1 = (const float*)d_in[9];

    float* out   = (float*)d_out;
    float* y_out = out;                               // [B][S][H] (layer1 y)
    float* hlast = out + (size_t)BB * SS * HH;        // [2][B][H]

    float* ws  = (float*)d_ws;
    float* pre = ws;                                  // [B][S][H] layer0 proj
    unsigned long long* hp0 = (unsigned long long*)(ws + (size_t)BB * SS * HH);
    unsigned long long* hp1 = hp0 + (size_t)2 * BB * HH;

    // Layer-0 input projection (embedding gather fused in)
    k_proj<EE><<<dim3(512, 8), 256, 0, stream>>>(nullptr, src, emb, W_ih0,
                                                 b_ih0, b_hh0, pre);
    // Fused pipelined 2-layer recurrence, batch-phased exchange
    k_rec_fused2<<<256, 512, 0, stream>>>(pre, W_hh0, W_ih1, W_hh1, b_ih1, b_hh1,
                                          y_out, hlast, hp0, hp1);
}

// Round 7
// 1993.220 us; speedup vs baseline: 1.3711x; 1.0637x over previous
//
#include <hip/hip_runtime.h>
#include <math.h>

#define BB 64
#define SS 512
#define EE 256
#define HH 512

// ---------------------------------------------------------------------------
// Projection GEMM (layer 0): out[m][n] = sum_k A[m][k]*Wih[n][k] + b1 + b2
// ---------------------------------------------------------------------------
template <int K>
__global__ __launch_bounds__(256) void k_proj(const float* __restrict__ Ain,
                                              const int* __restrict__ src,
                                              const float* __restrict__ emb,
                                              const float* __restrict__ Wih,
                                              const float* __restrict__ b1,
                                              const float* __restrict__ b2,
                                              float* __restrict__ out) {
    __shared__ __align__(16) float As[16][68];
    __shared__ __align__(16) float Bs[16][68];
    int tid = threadIdx.x;
    int m0 = blockIdx.x * 64;
    int n0 = blockIdx.y * 64;
    int tx = tid & 15, ty = tid >> 4;
    int lr = tid >> 2;
    int lc = (tid & 3) * 4;

    const float* arow;
    if (src) arow = emb + (size_t)src[m0 + lr] * EE;
    else     arow = Ain + (size_t)(m0 + lr) * K;
    const float* brow = Wih + (size_t)(n0 + lr) * K;

    float acc[4][4] = {};

    for (int k0 = 0; k0 < K; k0 += 16) {
        float4 av = *(const float4*)(arow + k0 + lc);
        float4 bv = *(const float4*)(brow + k0 + lc);
        __syncthreads();
        As[lc + 0][lr] = av.x; As[lc + 1][lr] = av.y;
        As[lc + 2][lr] = av.z; As[lc + 3][lr] = av.w;
        Bs[lc + 0][lr] = bv.x; Bs[lc + 1][lr] = bv.y;
        Bs[lc + 2][lr] = bv.z; Bs[lc + 3][lr] = bv.w;
        __syncthreads();
#pragma unroll
        for (int k = 0; k < 16; ++k) {
            float4 a = *(const float4*)&As[k][ty * 4];
            float4 b = *(const float4*)&Bs[k][tx * 4];
            acc[0][0] += a.x * b.x; acc[0][1] += a.x * b.y;
            acc[0][2] += a.x * b.z; acc[0][3] += a.x * b.w;
            acc[1][0] += a.y * b.x; acc[1][1] += a.y * b.y;
            acc[1][2] += a.y * b.z; acc[1][3] += a.y * b.w;
            acc[2][0] += a.z * b.x; acc[2][1] += a.z * b.y;
            acc[2][2] += a.z * b.z; acc[2][3] += a.z * b.w;
            acc[3][0] += a.w * b.x; acc[3][1] += a.w * b.y;
            acc[3][2] += a.w * b.z; acc[3][3] += a.w * b.w;
        }
    }

    int n = n0 + tx * 4;
    float bx_ = b1[n + 0] + b2[n + 0];
    float by_ = b1[n + 1] + b2[n + 1];
    float bz_ = b1[n + 2] + b2[n + 2];
    float bw_ = b1[n + 3] + b2[n + 3];
#pragma unroll
    for (int i = 0; i < 4; ++i) {
        int m = m0 + ty * 4 + i;
        float4 o;
        o.x = acc[i][0] + bx_; o.y = acc[i][1] + by_;
        o.z = acc[i][2] + bz_; o.w = acc[i][3] + bw_;
        *(float4*)(out + (size_t)m * HH + n) = o;
    }
}

// ---------------------------------------------------------------------------
// Fused 2-layer persistent recurrence, batch-phased, REGISTER-ONLY inner loop.
//
// Round-6 forensics: the FMA loop was ds_read-latency-throttled (192 weight
// regs leave no room to prefetch the 32 LDS broadcast reads per phase), and
// that cost is identical under any latency reshuffling. Fix: each wave polls
// ITS OWN k-eighth directly into lane-distributed VGPRs (lane l of wave w
// holds h0[w*64+l], h1[w*64+l]) and the matvec broadcasts in-register via
// v_readlane -> SGPR -> v_fmac. Inner loop = pure VALU, no LDS, no lgkm
// stalls; the h-LDS staging and one barrier per phase are gone.
//
// Tick t (t=1..512): phase A (batch 2c) then phase B (batch 2c+1); each
// phase computes h0_X(t) and h1_X(t-1) (1-step layer skew). 3 matvec units:
// W_hh0*h0, W_ih1*h0, W_hh1*h1. Grid 256 = 32 chunks x 8 row-slices;
// 512 thr = 64 rows x 8 k-eighths. Weights: 192 floats/thread in unified
// VGPR+AGPR file (launch_bounds(512,2) -> 256-reg cap, 1 block/CU, all
// 256 blocks co-resident).
//
// Exchange: tag-in-data {f32,u32 tag} 8B relaxed agent atomics, 2-slot
// per-layer buffers (hp0, hp1). Tick-t poll wants tag t in slot t&1;
// publish tag t+1 into slot (t+1)&1. 2-slot induction per batch chain:
// publishing tag t+1 requires passing the tag-t poll, which requires all
// group blocks published tag t, which requires they passed poll t-1 (the
// slot being overwritten). Reduce uses redA/redB double-buffer; the single
// barrier per phase orders red writes before waves 0-1 read them, and red_X
// is next rewritten only after the following phase's barrier.
// ---------------------------------------------------------------------------
__device__ __forceinline__ void rec_phase3(
    int t, int bX, int grow, int r, int w, int kown,
    const float* __restrict__ pre,
    const float* w0f, const float* waf, const float* wbf, float bias1,
    unsigned long long* __restrict__ hp0, unsigned long long* __restrict__ hp1,
    float (*red)[3][64],
    float* __restrict__ y, float& h0last, float& h1last) {
    // prefetch this batch's pre value (wave 0 only; hides under poll+FMA)
    float pv = 0.f;
    if (w == 0 && t < SS) pv = pre[((size_t)bX * SS + t) * HH + grow];

    // poll own k-eighth: lane r of wave w owns k = w*64+r (1 pair per buffer)
    const unsigned long long* s0p =
        hp0 + (size_t)(t & 1) * BB * HH + (size_t)bX * HH + kown;
    const unsigned long long* s1p =
        hp1 + (size_t)(t & 1) * BB * HH + (size_t)bX * HH + kown;
    unsigned long long q0, q1;
    const unsigned tt = (unsigned)t;
    for (;;) {
        q0 = __hip_atomic_load(s0p, __ATOMIC_RELAXED, __HIP_MEMORY_SCOPE_AGENT);
        q1 = __hip_atomic_load(s1p, __ATOMIC_RELAXED, __HIP_MEMORY_SCOPE_AGENT);
        unsigned d = (((unsigned)(q0 >> 32)) ^ tt) | (((unsigned)(q1 >> 32)) ^ tt);
        if (d == 0) break;
    }
    const int h0i = (int)(unsigned)q0;   // h0[bX][w*64+r] bits
    const int h1i = (int)(unsigned)q1;   // h1[bX][w*64+r] bits

    // pure-register matvec: in-wave broadcast via readlane (wave-uniform SGPR)
    float aa = 0.f, ai = 0.f, ah = 0.f;
#pragma unroll
    for (int k = 0; k < 64; ++k) {
        float s0 = __int_as_float(__builtin_amdgcn_readlane(h0i, k));
        float s1 = __int_as_float(__builtin_amdgcn_readlane(h1i, k));
        aa = fmaf(w0f[k], s0, aa);
        ai = fmaf(waf[k], s0, ai);
        ah = fmaf(wbf[k], s1, ah);
    }
    red[w][0][r] = aa; red[w][1][r] = ai; red[w][2][r] = ah;
    __syncthreads();

    // finalize: wave 0 -> h0_X(t); wave 1 -> h1_X(t-1); others run ahead
    if (w == 0) {
        if (t < SS) {
            float s0 = red[0][0][r] + red[1][0][r] + red[2][0][r] + red[3][0][r] +
                       red[4][0][r] + red[5][0][r] + red[6][0][r] + red[7][0][r];
            float h0v = tanhf(pv + s0);
            h0last = h0v;
            unsigned long long pk =
                ((unsigned long long)(unsigned)(t + 1) << 32) |
                (unsigned long long)__float_as_uint(h0v);
            __hip_atomic_store(&hp0[(size_t)((t + 1) & 1) * BB * HH + (size_t)bX * HH + grow],
                               pk, __ATOMIC_RELAXED, __HIP_MEMORY_SCOPE_AGENT);
        }
    } else if (w == 1) {
        float si = red[0][1][r] + red[1][1][r] + red[2][1][r] + red[3][1][r] +
                   red[4][1][r] + red[5][1][r] + red[6][1][r] + red[7][1][r];
        float sh = red[0][2][r] + red[1][2][r] + red[2][2][r] + red[3][2][r] +
                   red[4][2][r] + red[5][2][r] + red[6][2][r] + red[7][2][r];
        float h1v = tanhf(si + sh + bias1);
        h1last = h1v;
        y[((size_t)bX * SS + (t - 1)) * HH + grow] = h1v;
        if (t < SS) {
            unsigned long long pk =
                ((unsigned long long)(unsigned)(t + 1) << 32) |
                (unsigned long long)__float_as_uint(h1v);
            __hip_atomic_store(&hp1[(size_t)((t + 1) & 1) * BB * HH + (size_t)bX * HH + grow],
                               pk, __ATOMIC_RELAXED, __HIP_MEMORY_SCOPE_AGENT);
        }
    }
}

__global__ __launch_bounds__(512, 2) void k_rec_fused3(
    const float* __restrict__ pre,       // [B][S][H] layer0 input projection
    const float* __restrict__ Whh0,
    const float* __restrict__ Wih1,
    const float* __restrict__ Whh1,
    const float* __restrict__ b_ih1,
    const float* __restrict__ b_hh1,
    float* __restrict__ y,               // [B][S][H] layer1 output
    float* __restrict__ hlast,           // [2][B][H]
    unsigned long long* __restrict__ hp0,
    unsigned long long* __restrict__ hp1) {
    __shared__ __align__(16) float redA[8][3][64], redB[8][3][64];

    const int tid = threadIdx.x;
    const int r = tid & 63;
    const int w = tid >> 6;              // k-eighth 0..7
    const int bid = blockIdx.x;
    const int g = bid & 7;               // row slice (consecutive bids -> XCD spread)
    const int c = bid >> 3;              // batch chunk
    const int grow = g * 64 + r;
    const int kown = w * 64 + r;         // the k-index this thread polls/owns
    const int bA = c * 2, bB = c * 2 + 1;

    // three 64x512 weight slices -> scalar register arrays (one-time)
    float w0f[64], waf[64], wbf[64];
    {
        const float* p0 = Whh0 + (size_t)grow * HH + w * 64;
        const float* pa = Wih1 + (size_t)grow * HH + w * 64;
        const float* pb = Whh1 + (size_t)grow * HH + w * 64;
#pragma unroll
        for (int i = 0; i < 16; ++i) {
            float4 a4 = *(const float4*)(p0 + i * 4);
            float4 b4 = *(const float4*)(pa + i * 4);
            float4 c4 = *(const float4*)(pb + i * 4);
            w0f[4*i+0] = a4.x; w0f[4*i+1] = a4.y; w0f[4*i+2] = a4.z; w0f[4*i+3] = a4.w;
            waf[4*i+0] = b4.x; waf[4*i+1] = b4.y; waf[4*i+2] = b4.z; waf[4*i+3] = b4.w;
            wbf[4*i+0] = c4.x; wbf[4*i+1] = c4.y; wbf[4*i+2] = c4.z; wbf[4*i+3] = c4.w;
        }
    }

    // ---- prologue: per batch, h0(0)=tanh(pre[0]) tag 1; h1(-1)=0 tag 1 ----
    float h0lA = 0.f, h0lB = 0.f, h1lA = 0.f, h1lB = 0.f, bias1 = 0.f;
    if (w == 0) {
        float pA = pre[(size_t)bA * SS * HH + grow];
        h0lA = tanhf(pA);
        unsigned long long pk = ((unsigned long long)1u << 32) |
                                (unsigned long long)__float_as_uint(h0lA);
        __hip_atomic_store(&hp0[(size_t)1 * BB * HH + (size_t)bA * HH + grow], pk,
                           __ATOMIC_RELAXED, __HIP_MEMORY_SCOPE_AGENT);
        float pB = pre[(size_t)bB * SS * HH + grow];
        h0lB = tanhf(pB);
        pk = ((unsigned long long)1u << 32) |
             (unsigned long long)__float_as_uint(h0lB);
        __hip_atomic_store(&hp0[(size_t)1 * BB * HH + (size_t)bB * HH + grow], pk,
                           __ATOMIC_RELAXED, __HIP_MEMORY_SCOPE_AGENT);
    } else if (w == 1) {
        bias1 = b_ih1[grow] + b_hh1[grow];
        unsigned long long pk = ((unsigned long long)1u << 32);  // h1(-1)=0
        __hip_atomic_store(&hp1[(size_t)1 * BB * HH + (size_t)bA * HH + grow], pk,
                           __ATOMIC_RELAXED, __HIP_MEMORY_SCOPE_AGENT);
        __hip_atomic_store(&hp1[(size_t)1 * BB * HH + (size_t)bB * HH + grow], pk,
                           __ATOMIC_RELAXED, __HIP_MEMORY_SCOPE_AGENT);
    }

    for (int t = 1; t <= SS; ++t) {
        // phase A (batch 2c): tag-t data published one B-phase ago
        rec_phase3(t, bA, grow, r, w, kown, pre, w0f, waf, wbf, bias1,
                   hp0, hp1, redA, y, h0lA, h1lA);
        // phase B (batch 2c+1): tag-t data published one A-phase ago
        rec_phase3(t, bB, grow, r, w, kown, pre, w0f, waf, wbf, bias1,
                   hp0, hp1, redB, y, h0lB, h1lB);
    }

    if (w == 0) {
        hlast[(size_t)bA * HH + grow] = h0lA;                        // layer0
        hlast[(size_t)bB * HH + grow] = h0lB;
    } else if (w == 1) {
        hlast[(size_t)BB * HH + (size_t)bA * HH + grow] = h1lA;      // layer1
        hlast[(size_t)BB * HH + (size_t)bB * HH + grow] = h1lB;
    }
}

// ---------------------------------------------------------------------------
extern "C" void kernel_launch(void* const* d_in, const int* in_sizes, int n_in,
                              void* d_out, int out_size, void* d_ws, size_t ws_size,
                              hipStream_t stream) {
    const int*   src   = (const int*)d_in[0];
    const float* emb   = (const float*)d_in[1];
    const float* W_ih0 = (const float*)d_in[2];
    const float* W_hh0 = (const float*)d_in[3];
    const float* b_ih0 = (const float*)d_in[4];
    const float* b_hh0 = (const float*)d_in[5];
    const float* W_ih1 = (const float*)d_in[6];
    const float* W_hh1 = (const float*)d_in[7];
    const float* b_ih1 = (const float*)d_in[8];
    const float* b_hh1 = (const float*)d_in[9];

    float* out   = (float*)d_out;
    float* y_out = out;                               // [B][S][H] (layer1 y)
    float* hlast = out + (size_t)BB * SS * HH;        // [2][B][H]

    float* ws  = (float*)d_ws;
    float* pre = ws;                                  // [B][S][H] layer0 proj
    unsigned long long* hp0 = (unsigned long long*)(ws + (size_t)BB * SS * HH);
    unsigned long long* hp1 = hp0 + (size_t)2 * BB * HH;

    // Layer-0 input projection (embedding gather fused in)
    k_proj<EE><<<dim3(512, 8), 256, 0, stream>>>(nullptr, src, emb, W_ih0,
                                                 b_ih0, b_hh0, pre);
    // Fused pipelined 2-layer recurrence, batch-phased, register-only loop
    k_rec_fused3<<<256, 512, 0, stream>>>(pre, W_hh0, W_ih1, W_hh1, b_ih1, b_hh1,
                                          y_out, hlast, hp0, hp1);
}